// Round 12
// baseline (1058.247 us; speedup 1.0000x reference)
//
#include <hip/hip_runtime.h>
#include <hip/hip_bf16.h>
#include <cstdint>
#include <cstddef>

#define A_REAL 50000
#define A_PAD  50048      // 391 * 128
#define MT128  391
#define NBOND  6
#define HD     512
#define FATOM  133
#define FBOND  14
#define KWI    160        // f_atoms block width (133 padded)
#define KU     704        // weight row: nei(512) | bond(32) | f_atoms(160)
#define KST    192        // wU static row: bond(32) | fa(160)
#define NMOL   2000
#define MOLPAD 2048
#define APM    25
#define NHID   256

typedef __bf16 bf16x8 __attribute__((ext_vector_type(8)));
typedef float  f32x4  __attribute__((ext_vector_type(4)));
typedef short  short8 __attribute__((ext_vector_type(8)));
typedef short  short4v __attribute__((ext_vector_type(4)));

__device__ __forceinline__ float b2f(unsigned short u) {
  return __uint_as_float(((unsigned int)u) << 16);
}
__device__ __forceinline__ unsigned short f2b(float f) {
  unsigned int x = __float_as_uint(f);
  unsigned int r = (x + 0x7fffu + ((x >> 16) & 1u)) >> 16;
  return (unsigned short)r;
}
__device__ __forceinline__ unsigned short f2h(float f) {
  _Float16 h = (_Float16)f;                 // v_cvt_f16_f32, RNE
  return *(unsigned short*)&h;
}
__device__ __forceinline__ float h2f(unsigned short u) {
  _Float16 h = *(_Float16*)&u;
  return (float)h;
}

// ---------------- zero wEnc pad rows (rows 2000..2047) -----------------------
__global__ void zero_enc(unsigned short* __restrict__ wEnc)
{
  const int t = blockIdx.x * 256 + threadIdx.x;
  if (t < 48 * 1024) wEnc[(size_t)NMOL * 1024 + t] = 0;
}

// ---------------- f32 weights -> padded bf16 ---------------------------------
// mode 0: plain pad to ldd (Wi [512][133] -> [512][KWI], FFN1 [256][1024]).
// mode 1: Wo [512][645]=[f_atoms|a_msg] -> KU layout:
//         k<512 = a_msg part (src 133+k), 512..543 = 0, 544..676 = f_atoms.
// mode 2: Wh+Wi combined -> KU layout:
//         k<526 = Wh (src k; 512 nei + 14 bond), 526..543 = 0,
//         544..676 = Wi (srcB k-544).
__global__ void convw(unsigned short* __restrict__ dst, const float* __restrict__ src,
                      const float* __restrict__ srcB,
                      int Ksrc, int ldd, int rows, int mode)
{
  const int idx = blockIdx.x * 256 + threadIdx.x;
  if (idx >= rows * ldd) return;
  const int n = idx / ldd, k = idx % ldd;
  float v = 0.f;
  if (mode == 0) {
    if (k < Ksrc) v = src[(size_t)n * Ksrc + k];
  } else if (mode == 1) {
    if (k < 512)                  v = src[(size_t)n * 645 + 133 + k];
    else if (k >= 544 && k < 677) v = src[(size_t)n * 645 + (k - 544)];
  } else {
    if (k < 526)                  v = src[(size_t)n * 526 + k];
    else if (k >= 544 && k < 677) v = srcB[(size_t)n * 133 + (k - 544)];
  }
  dst[(size_t)n * ldd + k] = f2b(v);
}

// ---------------- combined bias bh + bi (f32) --------------------------------
__global__ void bias_comb(float* __restrict__ dst, const float* __restrict__ bh,
                          const float* __restrict__ bi)
{
  const int t = blockIdx.x * 256 + threadIdx.x;
  if (t < HD) dst[t] = bh[t] + bi[t];
}

// ---------------- f_atoms -> wU cols 32..191 (bf16, padded) ------------------
__global__ void atoms_prep(unsigned short* __restrict__ wU, const float* __restrict__ f_atoms)
{
  const int idx = blockIdx.x * 256 + threadIdx.x;
  if (idx >= A_REAL * KWI) return;
  const int r = idx / KWI, c = idx % KWI;
  float v = 0.f;
  if (c < FATOM) v = f_atoms[(size_t)r * FATOM + c];
  wU[(size_t)r * KST + 32 + c] = f2b(v);
}

// ---------------- bond gather-sum -> wU cols 0..31 (once per side) -----------
__global__ void bond_gather(unsigned short* __restrict__ wU, const float* __restrict__ f_bonds,
                            const int* __restrict__ a2b)
{
  const int a = blockIdx.x * 256 + threadIdx.x;
  if (a >= A_REAL) return;
  float acc[FBOND];
  #pragma unroll
  for (int c = 0; c < FBOND; ++c) acc[c] = 0.f;
  #pragma unroll
  for (int j = 0; j < NBOND; ++j) {
    const int b = a2b[a * NBOND + j];
    const float* row = f_bonds + (size_t)b * FBOND;
    #pragma unroll
    for (int c = 0; c < FBOND; ++c) acc[c] += row[c];
  }
  unsigned short* d = wU + (size_t)a * KST;
  #pragma unroll
  for (int c = 0; c < FBOND; ++c) d[c] = f2b(acc[c]);
  #pragma unroll
  for (int c = FBOND; c < 32; ++c) d[c] = 0;
}

// ============ FUSED gather+GEMM: C[M x 512] = A[M x K] * W[512 x K]^T ========
// BM=128, BN=512 (full N -> NO gather amplification), BK=32, 8 waves (2Mx4N).
// The A-operand's nei part (k<512) is the 6-neighbor relu-sum of fp16 state,
// computed ON THE FLY during staging (replaces the 4 standalone gather
// dispatches, ~350us serial, now overlapped with MFMA). Static part
// (k>=512) staged from wU=[bond|fa] (192 cols, bf16).
// All staging reg-staged (plain loads; compiler emits counted vmcnt) with
// depth-1 prefetch: issue t+1 loads after ds_write(t), consume after next
// barrier -> full-K-step latency cover. LDS row stride padded to 40 ushorts
// (80B): (5r+c)%8 uniform -> b128 reads AND writes bank-conflict-free.
// One barrier per K-step (ring-2 WAR safe: write(t+1,buf^1) happens-after
// barrier(t) happens-after all reads(t-1,buf^1)).
// Numerics: identical op multiset/order to the split version (f32 nei sum
// in a2a order -> f2b; fp32 MFMA accum; f2h output) -> absmax unchanged.
// MODE 0: out = fp16(acc + bias)  (pre-relu state)
// MODE 2: out = fp16(relu(acc + bias))  (Wo)
struct FusedP {
  const unsigned short* state; unsigned long long sState;  // fp16 [A_REAL][512]
  const unsigned short* statB; unsigned long long sStatB;  // bf16 [A_REAL][192]
  const unsigned short* W; unsigned long long sW; int ldb;
  const float* bias0; const float* bias1;
  unsigned short* out; unsigned long long sOut;            // fp16 [A_REAL][512]
  const int* a2a0; const int* a2a1;
  int nt;
};

template<int MODE, int NEI>
__launch_bounds__(512, 2)
__global__ void gemm_fused(FusedP p)
{
  __shared__ alignas(16) unsigned short lA[2][128 * 40];
  __shared__ alignas(16) unsigned short lB[2][512 * 40];
  const int tid  = threadIdx.x;
  const int lane = tid & 63;
  const int wav  = tid >> 6;
  const int wm = wav >> 2, wn = wav & 3;

  // bijective chunked XCD swizzle (m204); nwg = 782 (not %8==0)
  const int nwg = gridDim.x;
  const int id  = blockIdx.x;
  const int q = nwg >> 3, r = nwg & 7;
  const int xcd = id & 7, jj = id >> 3;
  const int gid = (xcd < r ? xcd * (q + 1) : r * (q + 1) + (xcd - r) * q) + jj;
  const int bps = nwg >> 1;                 // 391 blocks per side
  const int side = gid / bps;
  const int bxt  = gid - side * bps;
  const size_t tileM = (size_t)bxt * 128;

  const int srow = tid >> 2;                // staging row 0..127
  const int sc8  = (tid & 3) * 8;           // staging col chunk (8 bf16 = 16B)
  const size_t grow = tileM + srow;
  const bool rowOK = grow < A_REAL;
  const size_t growS = rowOK ? grow : 0;    // safe dummy row

  const unsigned short* state = p.state + side * p.sState;
  const unsigned short* statB = p.statB + side * p.sStatB + growS * KST;
  const unsigned short* W     = p.W + side * p.sW;
  unsigned short* out         = p.out + side * p.sOut;
  const float* bias = side ? p.bias1 : p.bias0;
  const int ldb = p.ldb;
  const int nt  = p.nt;

  int nidx[6];
  if (NEI) {
    const int* a2a = side ? p.a2a1 : p.a2a0;
    #pragma unroll
    for (int j = 0; j < NBOND; ++j)
      nidx[j] = rowOK ? a2a[grow * NBOND + j] : 0;
  }

  short8 pA[6];
  short8 pB[4];
  auto issueA = [&](int t) {
    if (NEI && t < NEI) {
      #pragma unroll
      for (int j = 0; j < NBOND; ++j)
        pA[j] = *reinterpret_cast<const short8*>(state + (size_t)nidx[j] * HD + t * 32 + sc8);
    } else {
      pA[0] = *reinterpret_cast<const short8*>(statB + (t - NEI) * 32 + sc8);
    }
  };
  auto issueB = [&](int t) {
    #pragma unroll
    for (int i = 0; i < 4; ++i)
      pB[i] = *reinterpret_cast<const short8*>(W + (size_t)(i * 128 + srow) * ldb + t * 32 + sc8);
  };

  f32x4 acc[4][8];
  #pragma unroll
  for (int m = 0; m < 4; ++m)
    #pragma unroll
    for (int n = 0; n < 8; ++n)
      acc[m][n] = (f32x4){0.f, 0.f, 0.f, 0.f};

  issueA(0); issueB(0);

  const int fr  = lane & 15;
  const int fk8 = (lane >> 4) * 8;

  for (int t = 0; t < nt; ++t) {
    const int buf = t & 1;
    short8 st;
    if (NEI && t < NEI) {
      float s[8];
      #pragma unroll
      for (int e = 0; e < 8; ++e) s[e] = 0.f;
      #pragma unroll
      for (int j = 0; j < NBOND; ++j)
        #pragma unroll
        for (int e = 0; e < 8; ++e)
          s[e] += fmaxf(h2f((unsigned short)pA[j][e]), 0.f);
      #pragma unroll
      for (int e = 0; e < 8; ++e) st[e] = rowOK ? (short)f2b(s[e]) : (short)0;
    } else {
      st = pA[0];
      if (!rowOK) st = (short8){0,0,0,0,0,0,0,0};
    }
    *reinterpret_cast<short8*>(&lA[buf][srow * 40 + sc8]) = st;
    #pragma unroll
    for (int i = 0; i < 4; ++i)
      *reinterpret_cast<short8*>(&lB[buf][(i * 128 + srow) * 40 + sc8]) = pB[i];

    // prefetch next K-step (consumed after the NEXT barrier: full-step cover)
    if (t + 1 < nt) { issueA(t + 1); issueB(t + 1); }

    asm volatile("s_waitcnt lgkmcnt(0)" ::: "memory");
    __builtin_amdgcn_s_barrier();
    asm volatile("" ::: "memory");

    bf16x8 af[4];
    #pragma unroll
    for (int m = 0; m < 4; ++m)
      af[m] = *reinterpret_cast<const bf16x8*>(&lA[buf][(wm * 64 + m * 16 + fr) * 40 + fk8]);
    __builtin_amdgcn_s_setprio(1);
    #pragma unroll
    for (int h = 0; h < 2; ++h) {
      bf16x8 bf[4];
      #pragma unroll
      for (int n = 0; n < 4; ++n)
        bf[n] = *reinterpret_cast<const bf16x8*>(
            &lB[buf][(wn * 128 + (h * 4 + n) * 16 + fr) * 40 + fk8]);
      #pragma unroll
      for (int m = 0; m < 4; ++m)
        #pragma unroll
        for (int n = 0; n < 4; ++n)
          acc[m][h * 4 + n] = __builtin_amdgcn_mfma_f32_16x16x32_bf16(
              bf[n], af[m], acc[m][h * 4 + n], 0, 0, 0);
    }
    __builtin_amdgcn_s_setprio(0);
    __builtin_amdgcn_s_barrier();
  }

  // epilogue: operand-swapped layout -> lane = M-row, 4 regs = 4 consec cols
  const int erow = lane & 15;
  const int ecol = (lane >> 4) * 4;
  #pragma unroll
  for (int m = 0; m < 4; ++m) {
    const size_t rowg = tileM + wm * 64 + m * 16 + erow;
    if (rowg >= A_REAL) continue;
    #pragma unroll
    for (int n = 0; n < 8; ++n) {
      const int colg = wn * 128 + n * 16 + ecol;
      const f32x4 bv = *reinterpret_cast<const f32x4*>(&bias[colg]);
      float v[4];
      #pragma unroll
      for (int e = 0; e < 4; ++e) v[e] = acc[m][n][e] + bv[e];
      short4v o;
      if (MODE == 0) {
        #pragma unroll
        for (int e = 0; e < 4; ++e) o[e] = (short)f2h(v[e]);
      } else {
        #pragma unroll
        for (int e = 0; e < 4; ++e) o[e] = (short)f2h(fmaxf(v[e], 0.f));
      }
      *reinterpret_cast<short4v*>(&out[rowg * (size_t)HD + colg]) = o;
    }
  }
}

// ---------------- small GEMM for FFN1 (r11 structure, 16 blocks) -------------
struct GemmP {
  const unsigned short* A; unsigned long long sA; int lda;
  const unsigned short* W; unsigned long long sW; int ldb;
  const float* bias0; const float* bias1;
  unsigned short* outA; unsigned long long sOutA;
  int outLd; int K; int bps;
};

template<int MODE, int NTN>
__launch_bounds__(512, 4)
__global__ void gemm_small(GemmP p)
{
  __shared__ alignas(16) unsigned short lA[2][256 * 32];
  __shared__ alignas(16) unsigned short lB[2][128 * 32];
  const int tid  = threadIdx.x;
  const int lane = tid & 63;
  const int wav  = tid >> 6;
  const int wm = wav >> 1, wn = wav & 1;
  const int gid = blockIdx.x;
  const int side = gid / p.bps;
  const int lid  = gid - side * p.bps;
  const int bxt = lid / NTN;
  const int byt = lid - bxt * NTN;
  const size_t tileM = (size_t)bxt * 256;
  const int n0 = byt * 128;
  const float* bias = side ? p.bias1 : p.bias0;
  const unsigned short* Aside = p.A + side * p.sA;
  const unsigned short* Wside = p.W + side * p.sW;
  unsigned short* outA = p.outA + side * p.sOutA;
  const int srow = tid >> 2;
  const int sc8 = (tid & 3) * 8;
  const int fr = lane & 15;
  const int fk = (lane >> 4) * 8;
  f32x4 acc[4][4];
  #pragma unroll
  for (int m = 0; m < 4; ++m)
    #pragma unroll
    for (int n = 0; n < 4; ++n)
      acc[m][n] = (f32x4){0.f, 0.f, 0.f, 0.f};
  const unsigned short* Abase = Aside + tileM * (size_t)p.lda;
  const unsigned short* Wbase = Wside + (size_t)n0 * (size_t)p.ldb;
  const int lda = p.lda, ldb = p.ldb;
  const int nt = p.K >> 5;
  auto stage = [&](int t, int buf) {
    const int k0 = t * 32;
    #pragma unroll
    for (int i = 0; i < 2; ++i) {
      const int rr = i * 128 + srow;
      const unsigned short* ga = Abase + (size_t)rr * lda + (k0 + sc8);
      __builtin_amdgcn_global_load_lds(
          (const __attribute__((address_space(1))) unsigned int*)ga,
          (__attribute__((address_space(3))) unsigned int*)&lA[buf][rr * 32 + sc8], 16, 0, 0);
    }
    const unsigned short* gb = Wbase + (size_t)srow * ldb + (k0 + sc8);
    __builtin_amdgcn_global_load_lds(
        (const __attribute__((address_space(1))) unsigned int*)gb,
        (__attribute__((address_space(3))) unsigned int*)&lB[buf][srow * 32 + sc8], 16, 0, 0);
  };
  stage(0, 0);
  int buf = 0;
  for (int t = 0; t < nt; ++t) {
    asm volatile("s_waitcnt vmcnt(0)" ::: "memory");
    __builtin_amdgcn_s_barrier();
    asm volatile("" ::: "memory");
    bf16x8 af[4], bfm[4];
    #pragma unroll
    for (int m = 0; m < 4; ++m)
      af[m] = *reinterpret_cast<const bf16x8*>(&lA[buf][(wm * 64 + m * 16 + fr) * 32 + fk]);
    #pragma unroll
    for (int n = 0; n < 4; ++n)
      bfm[n] = *reinterpret_cast<const bf16x8*>(&lB[buf][(wn * 64 + n * 16 + fr) * 32 + fk]);
    if (t + 1 < nt) stage(t + 1, buf ^ 1);
    #pragma unroll
    for (int m = 0; m < 4; ++m)
      #pragma unroll
      for (int n = 0; n < 4; ++n)
        acc[m][n] = __builtin_amdgcn_mfma_f32_16x16x32_bf16(bfm[n], af[m], acc[m][n], 0, 0, 0);
    buf ^= 1;
  }
  const int erow = lane & 15;
  const int ecol = (lane >> 4) * 4;
  #pragma unroll
  for (int m = 0; m < 4; ++m) {
    const size_t rowg = tileM + wm * 64 + m * 16 + erow;
    #pragma unroll
    for (int n = 0; n < 4; ++n) {
      const int colg = n0 + wn * 64 + n * 16 + ecol;
      const f32x4 bv = *reinterpret_cast<const f32x4*>(&bias[colg]);
      const size_t off = rowg * (size_t)p.outLd + colg;
      float v[4];
      #pragma unroll
      for (int e = 0; e < 4; ++e) v[e] = acc[m][n][e] + bv[e];
      short4v o;
      if (MODE == 0) {
        #pragma unroll
        for (int e = 0; e < 4; ++e) o[e] = (short)f2h(v[e]);
      } else {
        #pragma unroll
        for (int e = 0; e < 4; ++e) o[e] = (short)f2h(fmaxf(v[e], 0.f));
      }
      *reinterpret_cast<short4v*>(&outA[off]) = o;
    }
  }
}

// ---------------- per-molecule mean over 25 atoms -> enc (bf16), dual-side ---
__launch_bounds__(256)
__global__ void readout(const unsigned short* __restrict__ h, unsigned long long sH,
                        unsigned short* __restrict__ enc, int bps)
{
  const int blk = blockIdx.x;
  const int s   = blk / bps;
  const int mol = blk - s * bps;
  const int t = threadIdx.x;
  const unsigned short* base = h + s * sH + (size_t)mol * APM * HD + t * 2;
  float s0 = 0.f, s1 = 0.f;
  #pragma unroll
  for (int r = 0; r < APM; ++r) {
    unsigned int v = *reinterpret_cast<const unsigned int*>(base + (size_t)r * HD);
    s0 += h2f((unsigned short)(v & 0xffffu));
    s1 += h2f((unsigned short)(v >> 16));
  }
  s0 *= (1.f / 25.f);
  s1 *= (1.f / 25.f);
  unsigned int o = (unsigned int)f2b(s0) | ((unsigned int)f2b(s1) << 16);
  *reinterpret_cast<unsigned int*>(enc + (size_t)mol * 1024 + s * HD + t * 2) = o;
}

// ---------------- final dot with ffn2 (ff1 is fp16) --------------------------
__launch_bounds__(256)
__global__ void ffn2_red(const unsigned short* __restrict__ ff1, const float* __restrict__ w2,
                         const float* __restrict__ b2, float* __restrict__ out)
{
  __shared__ float red[256];
  const int mol = blockIdx.x, t = threadIdx.x;
  red[t] = h2f(ff1[(size_t)mol * NHID + t]) * w2[t];
  __syncthreads();
  #pragma unroll
  for (int s = 128; s > 0; s >>= 1) {
    if (t < s) red[t] += red[t + s];
    __syncthreads();
  }
  if (t == 0) out[mol] = red[0] + b2[0];
}

// -----------------------------------------------------------------------------
extern "C" void kernel_launch(void* const* d_in, const int* in_sizes, int n_in,
                              void* d_out, int out_size, void* d_ws, size_t ws_size,
                              hipStream_t stream)
{
  (void)in_sizes; (void)n_in; (void)out_size; (void)ws_size;

  unsigned char* p = (unsigned char*)d_ws;
  auto take = [&](size_t bytes) -> unsigned short* {
    unsigned short* r = (unsigned short*)p;
    p += (bytes + 255) & ~(size_t)255;
    return r;
  };
  const unsigned long long sX = (unsigned long long)A_REAL * HD;   // elems
  const unsigned long long sU = (unsigned long long)A_REAL * KST;
  unsigned short* wSa  = take((size_t)2 * sX * 2);  // fp16 state ping
  unsigned short* wSb  = take((size_t)2 * sX * 2);  // fp16 state pong
  unsigned short* wU   = take((size_t)2 * sU * 2);  // bf16 [bond|fa]
  unsigned short* wEnc = take((size_t)MOLPAD * 1024 * 2);
  unsigned short* wFF1 = take((size_t)MOLPAD * NHID * 2);
  unsigned short* wWiB = take((size_t)2 * 512 * KWI * 2);
  unsigned short* wWhC = take((size_t)2 * 512 * KU * 2);
  unsigned short* wWoB = take((size_t)2 * 512 * KU * 2);
  unsigned short* wF1B = take((size_t)NHID * 1024 * 2);
  float*          wBC  = (float*)take((size_t)2 * HD * 4);

  const float* biasWi[2]; const float* biasWo[2];
  const int* a2aP[2];
  for (int s = 0; s < 2; ++s) {
    biasWi[s] = (const float*)d_in[s * 10 + 5];
    biasWo[s] = (const float*)d_in[s * 10 + 9];
    a2aP[s]   = (const int*)  d_in[s * 10 + 2];
  }

  zero_enc<<<192, 256, 0, stream>>>(wEnc);

  for (int side = 0; side < 2; ++side) {
    const float* f_atoms = (const float*)d_in[side * 10 + 0];
    const float* f_bonds = (const float*)d_in[side * 10 + 1];
    const int*   a2b     = (const int*)  d_in[side * 10 + 3];
    const float* Wi_w    = (const float*)d_in[side * 10 + 4];
    const float* Wi_b    = (const float*)d_in[side * 10 + 5];
    const float* Wh_w    = (const float*)d_in[side * 10 + 6];
    const float* Wh_b    = (const float*)d_in[side * 10 + 7];
    const float* Wo_w    = (const float*)d_in[side * 10 + 8];
    convw<<<(512 * KWI) / 256, 256, 0, stream>>>(wWiB + side * 512 * KWI, Wi_w, nullptr,
                                                 FATOM, KWI, 512, 0);
    convw<<<(512 * KU) / 256, 256, 0, stream>>>(wWhC + side * 512 * KU, Wh_w, Wi_w,
                                                526, KU, 512, 2);
    convw<<<(512 * KU) / 256, 256, 0, stream>>>(wWoB + side * 512 * KU, Wo_w, nullptr,
                                                645, KU, 512, 1);
    bias_comb<<<2, 256, 0, stream>>>(wBC + side * HD, Wh_b, Wi_b);
    atoms_prep<<<(A_REAL * KWI + 255) / 256, 256, 0, stream>>>(wU + side * sU, f_atoms);
    bond_gather<<<(A_REAL + 255) / 256, 256, 0, stream>>>(wU + side * sU, f_bonds, a2b);
  }

  const int NWG = MT128 * 2;    // 782 blocks, both sides
  FusedP f;
  // Wi: s0 = fa @ Wi^T + bi  -> wSa   (static-only, K=160)
  f = { wSa, sX, wU + 32, sU, wWiB, 512ull * KWI, KWI,
        biasWi[0], biasWi[1], wSa, sX, a2aP[0], a2aP[1], KWI / 32 };
  gemm_fused<0, 0><<<NWG, 512, 0, stream>>>(f);
  // 3x WhC: s' = [gather(relu s)|bond|fa] @ [Wh|0|Wi]^T + (bh+bi)
  unsigned short* sin = wSa; unsigned short* sout = wSb;
  for (int it = 0; it < 3; ++it) {
    f = { sin, sX, wU, sU, wWhC, 512ull * KU, KU,
          wBC, wBC + HD, sout, sX, a2aP[0], a2aP[1], KU / 32 };
    gemm_fused<0, 16><<<NWG, 512, 0, stream>>>(f);
    unsigned short* tmp = sin; sin = sout; sout = tmp;
  }
  // Wo: h = relu([gather(relu s)|bond|fa] @ Wo'^T + bo)  (sin holds s3)
  f = { sin, sX, wU, sU, wWoB, 512ull * KU, KU,
        biasWo[0], biasWo[1], sout, sX, a2aP[0], a2aP[1], KU / 32 };
  gemm_fused<2, 16><<<NWG, 512, 0, stream>>>(f);
  readout<<<2 * NMOL, 256, 0, stream>>>(sout, sX, wEnc, NMOL);

  const float* ffn1_w = (const float*)d_in[20];
  const float* ffn1_b = (const float*)d_in[21];
  const float* ffn2_w = (const float*)d_in[22];
  const float* ffn2_b = (const float*)d_in[23];

  convw<<<(NHID * 1024) / 256, 256, 0, stream>>>(wF1B, ffn1_w, nullptr, 1024, 1024, NHID, 0);
  GemmP gf = { wEnc, 0, 1024, wF1B, 0, 1024,
               ffn1_b, ffn1_b, wFF1, 0, NHID, 1024, 16 };
  gemm_small<2, 2><<<16, 512, 0, stream>>>(gf);
  ffn2_red<<<NMOL, 256, 0, stream>>>(wFF1, ffn2_w, ffn2_b, (float*)d_out);
}

// Round 13
// 926.995 us; speedup vs baseline: 1.1416x; 1.1416x over previous
//
#include <hip/hip_runtime.h>
#include <hip/hip_bf16.h>
#include <cstdint>
#include <cstddef>

#define A_REAL 50000
#define A_PAD  50176      // 196 * 256
#define MT256  196
#define PADROWS 176
#define NBOND  6
#define HD     512
#define FATOM  133
#define FBOND  14
#define KWI    160        // f_atoms block width (133 padded)
#define KU     704        // unified row: nei(512) | bond(32) | f_atoms(160)
#define NMOL   2000
#define MOLPAD 2048
#define APM    25
#define NHID   256

typedef __bf16 bf16x8 __attribute__((ext_vector_type(8)));
typedef float  f32x4  __attribute__((ext_vector_type(4)));
typedef short  short8 __attribute__((ext_vector_type(8)));
typedef short  short4v __attribute__((ext_vector_type(4)));

__device__ __forceinline__ float b2f(unsigned short u) {
  return __uint_as_float(((unsigned int)u) << 16);
}
__device__ __forceinline__ unsigned short f2b(float f) {
  unsigned int x = __float_as_uint(f);
  unsigned int r = (x + 0x7fffu + ((x >> 16) & 1u)) >> 16;
  return (unsigned short)r;
}
__device__ __forceinline__ unsigned short f2h(float f) {
  _Float16 h = (_Float16)f;                 // v_cvt_f16_f32, RNE
  return *(unsigned short*)&h;
}
__device__ __forceinline__ float h2f(unsigned short u) {
  _Float16 h = *(_Float16*)&u;
  return (float)h;
}

// ---------------- zero pad rows of wU (both sides) + wEnc pad ----------------
__global__ void zero_pads(unsigned short* __restrict__ wU, unsigned long long sU,
                          unsigned short* __restrict__ wEnc)
{
  const int t = blockIdx.x * 256 + threadIdx.x;
  if (t < PADROWS * KU) {
    wU[(size_t)A_REAL * KU + t] = 0;
    wU[sU + (size_t)A_REAL * KU + t] = 0;
  }
  if (t < 48 * 1024) wEnc[(size_t)NMOL * 1024 + t] = 0;
}

// ---------------- f32 weights -> padded bf16 ---------------------------------
// mode 0: plain pad. mode 1: Wo -> KU layout. mode 2: Wh+Wi combined -> KU.
__global__ void convw(unsigned short* __restrict__ dst, const float* __restrict__ src,
                      const float* __restrict__ srcB,
                      int Ksrc, int ldd, int rows, int mode)
{
  const int idx = blockIdx.x * 256 + threadIdx.x;
  if (idx >= rows * ldd) return;
  const int n = idx / ldd, k = idx % ldd;
  float v = 0.f;
  if (mode == 0) {
    if (k < Ksrc) v = src[(size_t)n * Ksrc + k];
  } else if (mode == 1) {
    if (k < 512)                  v = src[(size_t)n * 645 + 133 + k];
    else if (k >= 544 && k < 677) v = src[(size_t)n * 645 + (k - 544)];
  } else {
    if (k < 526)                  v = src[(size_t)n * 526 + k];
    else if (k >= 544 && k < 677) v = srcB[(size_t)n * 133 + (k - 544)];
  }
  dst[(size_t)n * ldd + k] = f2b(v);
}

// ---------------- combined bias bh + bi (f32) --------------------------------
__global__ void bias_comb(float* __restrict__ dst, const float* __restrict__ bh,
                          const float* __restrict__ bi)
{
  const int t = blockIdx.x * 256 + threadIdx.x;
  if (t < HD) dst[t] = bh[t] + bi[t];
}

// ---------------- f_atoms -> wU cols 544..703 (bf16, padded) -----------------
__global__ void atoms_prep(unsigned short* __restrict__ wU, const float* __restrict__ f_atoms)
{
  const int idx = blockIdx.x * 256 + threadIdx.x;
  if (idx >= A_PAD * KWI) return;
  const int r = idx / KWI, c = idx % KWI;
  float v = 0.f;
  if (r < A_REAL && c < FATOM) v = f_atoms[(size_t)r * FATOM + c];
  wU[(size_t)r * KU + 544 + c] = f2b(v);
}

// ---------------- bond gather-sum -> wU cols 512..543 (once per side) --------
__global__ void bond_gather(unsigned short* __restrict__ wU, const float* __restrict__ f_bonds,
                            const int* __restrict__ a2b)
{
  const int a = blockIdx.x * 256 + threadIdx.x;
  if (a >= A_REAL) return;
  float acc[FBOND];
  #pragma unroll
  for (int c = 0; c < FBOND; ++c) acc[c] = 0.f;
  #pragma unroll
  for (int j = 0; j < NBOND; ++j) {
    const int b = a2b[a * NBOND + j];
    const float* row = f_bonds + (size_t)b * FBOND;
    #pragma unroll
    for (int c = 0; c < FBOND; ++c) acc[c] += row[c];
  }
  unsigned short* d = wU + (size_t)a * KU + 512;
  #pragma unroll
  for (int c = 0; c < FBOND; ++c) d[c] = f2b(acc[c]);
  #pragma unroll
  for (int c = FBOND; c < 32; ++c) d[c] = 0;
}

// ============ SLOT KERNEL: role-split co-dispatch ============================
// Every R-th block (bid%R==0, R=9 -> gemm blocks cycle XCDs) runs the r11
// single-side GEMM (256x128 tile, ring-2, T2 swizzle); all other blocks run
// the r11 gather (8 atoms/block, wave-per-atom, coalesced 1KB-row reads).
// The memory-bound gather hides under the GEMM's idle VMEM/MFMA gaps --
// overlapping sol's GEMM with solv's gather (independent chains) without
// changing EITHER kernel's proven memory access pattern (r12's fusion
// mistake). Numerics identical to r11 -> absmax must stay 0.015625.
// GEMM: C[M x N] = A[M x K] * W[N x K]^T, bf16 in, fp32 accum, fp16 out.
// MODE 0: out = fp16(acc + bias)   MODE 2: out = fp16(relu(acc + bias))
struct SlotP {
  // gemm role (single side, pre-resolved pointers)
  const unsigned short* A; int lda;
  const unsigned short* W; int ldb;
  const float* bias;
  unsigned short* out; int outLd;
  int K; int gB; int R;
  // gather role (other side), active when R > 1
  unsigned short* gDst;               // side's wU (nei cols 0..511)
  const unsigned short* gState;       // side's fp16 state
  const int* a2a;
};

template<int MODE, int NTN>
__launch_bounds__(512, 4)
__global__ void slot_kernel(SlotP p)
{
  __shared__ alignas(16) unsigned short lA[2][256 * 32];
  __shared__ alignas(16) unsigned short lB[2][128 * 32];
  const int tid = threadIdx.x;
  const int bid = blockIdx.x;

  int gi = bid;
  bool isg = true;
  int hi = 0;
  if (p.R > 1) {
    const int qq = bid / p.R, rr = bid - qq * p.R;
    if (rr == 0 && qq < p.gB) {
      gi = qq;
    } else {
      isg = false;
      hi = (qq < p.gB) ? (bid - qq - 1) : (bid - p.gB);
    }
  }

  if (!isg) {
    // ---- gather role: 8 atoms/block, wave-per-atom (r11 access pattern) ----
    const int wv   = tid >> 6;
    const int lane = tid & 63;
    const int a = hi * 8 + wv;
    if (a < A_REAL) {
      const int* idx = p.a2a + a * NBOND;
      float acc[8] = {0.f,0.f,0.f,0.f,0.f,0.f,0.f,0.f};
      #pragma unroll
      for (int j = 0; j < NBOND; ++j) {
        const int r0 = idx[j];
        short8 v = *reinterpret_cast<const short8*>(p.gState + (size_t)r0 * HD + lane * 8);
        #pragma unroll
        for (int e = 0; e < 8; ++e) acc[e] += fmaxf(h2f((unsigned short)v[e]), 0.f);
      }
      short8 o;
      #pragma unroll
      for (int e = 0; e < 8; ++e) o[e] = (short)f2b(acc[e]);
      *reinterpret_cast<short8*>(p.gDst + (size_t)a * KU + lane * 8) = o;
    }
    return;
  }

  // ---- gemm role: r11 body (ring-2, T2 swizzle, setprio) ----
  const int lane = tid & 63;
  const int wav  = tid >> 6;
  const int wm = wav >> 1, wn = wav & 1;

  // bijective chunked XCD swizzle over gemm sub-grid (gB % 8 == 0)
  const int nwg = p.gB;
  const int q2 = nwg >> 3, r2 = nwg & 7;
  const int xcd = gi & 7, jj = gi >> 3;
  const int gid = (xcd < r2 ? xcd * (q2 + 1) : r2 * (q2 + 1) + (xcd - r2) * q2) + jj;
  const int bxt = gid / NTN;
  const int byt = gid - bxt * NTN;
  const size_t tileM = (size_t)bxt * 256;
  const int n0 = byt * 128;

  const int srow = tid >> 2;
  const int sgcol = (((tid & 3) ^ ((tid >> 3) & 3)) * 8);  // T2 pre-swizzled chunk
  const int fr = lane & 15;
  const int xr = ((lane & 15) >> 1) & 3;
  const int fks = (((lane >> 4) ^ xr) * 8);

  f32x4 acc[4][4];
  #pragma unroll
  for (int m = 0; m < 4; ++m)
    #pragma unroll
    for (int n = 0; n < 4; ++n)
      acc[m][n] = (f32x4){0.f, 0.f, 0.f, 0.f};

  const unsigned short* Abase = p.A + tileM * (size_t)p.lda;
  const unsigned short* Wbase = p.W + (size_t)n0 * (size_t)p.ldb;
  const int lda = p.lda, ldb = p.ldb;
  const int nt = p.K >> 5;

  auto stage = [&](int t, int buf) {
    const int k0 = t * 32;
    #pragma unroll
    for (int i = 0; i < 2; ++i) {
      const int rr = i * 128 + srow;
      const unsigned short* ga = Abase + (size_t)rr * lda + (k0 + sgcol);
      __builtin_amdgcn_global_load_lds(
          (const __attribute__((address_space(1))) unsigned int*)ga,
          (__attribute__((address_space(3))) unsigned int*)&lA[buf][rr * 32 + (tid & 3) * 8], 16, 0, 0);
    }
    const unsigned short* gb = Wbase + (size_t)srow * ldb + (k0 + sgcol);
    __builtin_amdgcn_global_load_lds(
        (const __attribute__((address_space(1))) unsigned int*)gb,
        (__attribute__((address_space(3))) unsigned int*)&lB[buf][srow * 32 + (tid & 3) * 8], 16, 0, 0);
  };

  stage(0, 0);

  int buf = 0;
  for (int t = 0; t < nt; ++t) {
    asm volatile("s_waitcnt vmcnt(0)" ::: "memory");
    __builtin_amdgcn_s_barrier();
    asm volatile("" ::: "memory");

    bf16x8 af[4], bfm[4];
    #pragma unroll
    for (int m = 0; m < 4; ++m)
      af[m] = *reinterpret_cast<const bf16x8*>(&lA[buf][(wm * 64 + m * 16 + fr) * 32 + fks]);
    #pragma unroll
    for (int n = 0; n < 4; ++n)
      bfm[n] = *reinterpret_cast<const bf16x8*>(&lB[buf][(wn * 64 + n * 16 + fr) * 32 + fks]);

    if (t + 1 < nt) stage(t + 1, buf ^ 1);

    __builtin_amdgcn_s_setprio(1);
    // operand-swapped: lane = M-row, 4 acc regs = 4 consecutive N cols
    #pragma unroll
    for (int m = 0; m < 4; ++m)
      #pragma unroll
      for (int n = 0; n < 4; ++n)
        acc[m][n] = __builtin_amdgcn_mfma_f32_16x16x32_bf16(bfm[n], af[m], acc[m][n], 0, 0, 0);
    __builtin_amdgcn_s_setprio(0);

    buf ^= 1;
  }

  const int erow = lane & 15;
  const int ecol = (lane >> 4) * 4;
  #pragma unroll
  for (int m = 0; m < 4; ++m) {
    const size_t rowg = tileM + wm * 64 + m * 16 + erow;
    #pragma unroll
    for (int n = 0; n < 4; ++n) {
      const int colg = n0 + wn * 64 + n * 16 + ecol;
      const f32x4 bv = *reinterpret_cast<const f32x4*>(&p.bias[colg]);
      const size_t off = rowg * (size_t)p.outLd + colg;
      float v[4];
      #pragma unroll
      for (int e = 0; e < 4; ++e) v[e] = acc[m][n][e] + bv[e];
      short4v o;
      if (MODE == 0) {
        #pragma unroll
        for (int e = 0; e < 4; ++e) o[e] = (short)f2h(v[e]);
      } else {
        #pragma unroll
        for (int e = 0; e < 4; ++e) o[e] = (short)f2h(fmaxf(v[e], 0.f));
      }
      *reinterpret_cast<short4v*>(&p.out[off]) = o;
    }
  }
}

// ---------------- per-molecule mean over 25 atoms -> enc (bf16), dual-side ---
__launch_bounds__(256)
__global__ void readout(const unsigned short* __restrict__ h, unsigned long long sH,
                        unsigned short* __restrict__ enc, int bps)
{
  const int blk = blockIdx.x;
  const int s   = blk / bps;
  const int mol = blk - s * bps;
  const int t = threadIdx.x;
  const unsigned short* base = h + s * sH + (size_t)mol * APM * HD + t * 2;
  float s0 = 0.f, s1 = 0.f;
  #pragma unroll
  for (int r = 0; r < APM; ++r) {
    unsigned int v = *reinterpret_cast<const unsigned int*>(base + (size_t)r * HD);
    s0 += h2f((unsigned short)(v & 0xffffu));
    s1 += h2f((unsigned short)(v >> 16));
  }
  s0 *= (1.f / 25.f);
  s1 *= (1.f / 25.f);
  unsigned int o = (unsigned int)f2b(s0) | ((unsigned int)f2b(s1) << 16);
  *reinterpret_cast<unsigned int*>(enc + (size_t)mol * 1024 + s * HD + t * 2) = o;
}

// ---------------- final dot with ffn2 (ff1 is fp16) --------------------------
__launch_bounds__(256)
__global__ void ffn2_red(const unsigned short* __restrict__ ff1, const float* __restrict__ w2,
                         const float* __restrict__ b2, float* __restrict__ out)
{
  __shared__ float red[256];
  const int mol = blockIdx.x, t = threadIdx.x;
  red[t] = h2f(ff1[(size_t)mol * NHID + t]) * w2[t];
  __syncthreads();
  #pragma unroll
  for (int s = 128; s > 0; s >>= 1) {
    if (t < s) red[t] += red[t + s];
    __syncthreads();
  }
  if (t == 0) out[mol] = red[0] + b2[0];
}

// -----------------------------------------------------------------------------
extern "C" void kernel_launch(void* const* d_in, const int* in_sizes, int n_in,
                              void* d_out, int out_size, void* d_ws, size_t ws_size,
                              hipStream_t stream)
{
  (void)in_sizes; (void)n_in; (void)out_size; (void)ws_size;

  unsigned char* p = (unsigned char*)d_ws;
  auto take = [&](size_t bytes) -> unsigned short* {
    unsigned short* r = (unsigned short*)p;
    p += (bytes + 1023) & ~(size_t)1023;
    return r;
  };
  const unsigned long long sX = (unsigned long long)A_PAD * HD;   // elems
  const unsigned long long sU = (unsigned long long)A_PAD * KU;
  unsigned short* wS   = take((size_t)2 * sX * 2);   // fp16 state s / h
  unsigned short* wU   = take((size_t)2 * sU * 2);   // bf16 [nei|bond|f_atoms]
  unsigned short* wEnc = take((size_t)MOLPAD * 1024 * 2);   // bf16
  unsigned short* wFF1 = take((size_t)MOLPAD * NHID * 2);   // fp16
  unsigned short* wWiB = take((size_t)2 * 512 * KWI * 2);
  unsigned short* wWhC = take((size_t)2 * 512 * KU * 2);    // [Wh|0|Wi]
  unsigned short* wWoB = take((size_t)2 * 512 * KU * 2);
  unsigned short* wF1B = take((size_t)NHID * 1024 * 2);
  float*          wBC  = (float*)take((size_t)2 * HD * 4);  // bh+bi

  unsigned short* wS0 = wS;            unsigned short* wS1 = wS + sX;
  unsigned short* wU0 = wU;            unsigned short* wU1 = wU + sU;

  const float* biasWi[2]; const float* biasWo[2];
  const int* a2aP[2];
  for (int s = 0; s < 2; ++s) {
    biasWi[s] = (const float*)d_in[s * 10 + 5];
    biasWo[s] = (const float*)d_in[s * 10 + 9];
    a2aP[s]   = (const int*)  d_in[s * 10 + 2];
  }

  zero_pads<<<484, 256, 0, stream>>>(wU, sU, wEnc);

  for (int side = 0; side < 2; ++side) {
    const float* f_atoms = (const float*)d_in[side * 10 + 0];
    const float* f_bonds = (const float*)d_in[side * 10 + 1];
    const int*   a2b     = (const int*)  d_in[side * 10 + 3];
    const float* Wi_w    = (const float*)d_in[side * 10 + 4];
    const float* Wi_b    = (const float*)d_in[side * 10 + 5];
    const float* Wh_w    = (const float*)d_in[side * 10 + 6];
    const float* Wh_b    = (const float*)d_in[side * 10 + 7];
    const float* Wo_w    = (const float*)d_in[side * 10 + 8];
    convw<<<(512 * KWI) / 256, 256, 0, stream>>>(wWiB + side * 512 * KWI, Wi_w, nullptr,
                                                 FATOM, KWI, 512, 0);
    convw<<<(512 * KU) / 256, 256, 0, stream>>>(wWhC + side * 512 * KU, Wh_w, Wi_w,
                                                526, KU, 512, 2);
    convw<<<(512 * KU) / 256, 256, 0, stream>>>(wWoB + side * 512 * KU, Wo_w, nullptr,
                                                645, KU, 512, 1);
    bias_comb<<<2, 256, 0, stream>>>(wBC + side * HD, Wh_b, Wi_b);
    atoms_prep<<<(A_PAD * KWI) / 256, 256, 0, stream>>>(wU + side * sU, f_atoms);
    bond_gather<<<(A_REAL + 255) / 256, 256, 0, stream>>>(wU + side * sU, f_bonds, a2b);
  }

  const int GB = MT256 * 4;        // 784 gemm blocks (per side)
  const int RR = 9;                // gemm every 9th block -> XCD-cycling
  const int TOTAL = GB * RR;       // 7056: 784 gemm + 6272 gather (6250 used)

  unsigned short* uS[2] = { wU0, wU1 };
  unsigned short* sS[2] = { wS0, wS1 };
  const unsigned short* whc[2] = { wWhC, wWhC + 512 * KU };
  const unsigned short* wob[2] = { wWoB, wWoB + 512 * KU };
  const unsigned short* wib[2] = { wWiB, wWiB + 512 * KWI };
  const float* bc[2] = { wBC, wBC + HD };

  SlotP s;
  // S1: Wi_sol (gemm only)
  s = { uS[0] + 544, KU, wib[0], KWI, biasWi[0], sS[0], HD, KWI, GB, 1,
        nullptr, nullptr, nullptr };
  slot_kernel<0, 4><<<GB, 512, 0, stream>>>(s);
  // S2: Wi_solv + gather_sol(1)
  s = { uS[1] + 544, KU, wib[1], KWI, biasWi[1], sS[1], HD, KWI, GB, RR,
        uS[0], sS[0], a2aP[0] };
  slot_kernel<0, 4><<<TOTAL, 512, 0, stream>>>(s);
  // S3..S8: WhC iterations, staggered
  for (int it = 0; it < 3; ++it) {
    // gemm WhC_sol(it) + gather_solv(it+1 input)
    s = { uS[0], KU, whc[0], KU, bc[0], sS[0], HD, KU, GB, RR,
          uS[1], sS[1], a2aP[1] };
    slot_kernel<0, 4><<<TOTAL, 512, 0, stream>>>(s);
    if (it < 2) {
      s = { uS[1], KU, whc[1], KU, bc[1], sS[1], HD, KU, GB, RR,
            uS[0], sS[0], a2aP[0] };
      slot_kernel<0, 4><<<TOTAL, 512, 0, stream>>>(s);
    }
  }
  // S8: WhC3_solv + gather_sol(4)
  s = { uS[1], KU, whc[1], KU, bc[1], sS[1], HD, KU, GB, RR,
        uS[0], sS[0], a2aP[0] };
  slot_kernel<0, 4><<<TOTAL, 512, 0, stream>>>(s);
  // S9: Wo_sol + gather_solv(4)
  s = { uS[0], KU, wob[0], KU, biasWo[0], sS[0], HD, KU, GB, RR,
        uS[1], sS[1], a2aP[1] };
  slot_kernel<2, 4><<<TOTAL, 512, 0, stream>>>(s);
  // S10: Wo_solv (gemm only)
  s = { uS[1], KU, wob[1], KU, biasWo[1], sS[1], HD, KU, GB, 1,
        nullptr, nullptr, nullptr };
  slot_kernel<2, 4><<<GB, 512, 0, stream>>>(s);

  readout<<<2 * NMOL, 256, 0, stream>>>(wS, sX, wEnc, NMOL);

  const float* ffn1_w = (const float*)d_in[20];
  const float* ffn1_b = (const float*)d_in[21];
  const float* ffn2_w = (const float*)d_in[22];
  const float* ffn2_b = (const float*)d_in[23];

  convw<<<(NHID * 1024) / 256, 256, 0, stream>>>(wF1B, ffn1_w, nullptr, 1024, 1024, NHID, 0);
  s = { wEnc, 1024, wF1B, 1024, ffn1_b, wFF1, NHID, 1024, 16, 1,
        nullptr, nullptr, nullptr };
  slot_kernel<2, 2><<<16, 512, 0, stream>>>(s);
  ffn2_red<<<NMOL, 256, 0, stream>>>(wFF1, ffn2_w, ffn2_b, (float*)d_out);
}